// Round 2
// baseline (713.563 us; speedup 1.0000x reference)
//
#include <hip/hip_runtime.h>
#include <math.h>

#define NN 4096
#define DD 512
#define ELL 128

typedef unsigned long long u64;

// ---------------- build ELL for all 3 adjacency matrices ---------------------
struct Build3 {
  const float *adj0, *adj1, *adj2;
  int *c0, *c1, *c2;
  int *n0, *n1, *n2;
};

__global__ __launch_bounds__(256) void k_build3(Build3 p) {
  const int s = blockIdx.y;
  const float* adj = s == 0 ? p.adj0 : (s == 1 ? p.adj1 : p.adj2);
  int* cols = s == 0 ? p.c0 : (s == 1 ? p.c1 : p.c2);
  int* cnt  = s == 0 ? p.n0 : (s == 1 ? p.n1 : p.n2);
  const int wv = threadIdx.x >> 6;
  const int lane = threadIdx.x & 63;
  const int r = blockIdx.x * 4 + wv;
  const float* row = adj + (size_t)r * NN;
  int* rc = cols + (size_t)r * ELL;
  int base = 0;
  for (int c0 = 0; c0 < NN; c0 += 64) {
    float v = row[c0 + lane];
    u64 m = __ballot(v > 0.f);
    if (v > 0.f) {
      int idx = base + __popcll(m & ((1ull << lane) - 1ull));
      if (idx < ELL) rc[idx] = c0 + lane;
    }
    base += __popcll(m);
  }
  if (lane == 0) cnt[r] = base < ELL ? base : ELL;
}

// ---------------- dense f32 GEMM, 64x64 tile, 1 wave/block, dbuf LDS ---------
// C_m = A_m @ W_m + bscale(row) * b_m   (A: [4096x512], W: [512x512])
struct Gemm4 {
  const float *A0, *A1, *A2, *A3;
  const float *W0, *W1, *W2, *W3;
  const float *b0, *b1, *b2, *b3;
  float *C0, *C1, *C2, *C3;
  const int* bscale;   // per-row bias multiplier (degree); nullptr -> 1.0
};

__global__ __launch_bounds__(64) void k_gemm64(Gemm4 p) {
  __shared__ __align__(16) float As[2][16][68];  // [buf][k][m]
  __shared__ __align__(16) float Bs[2][16][68];  // [buf][k][n]
  const int lane = threadIdx.x;
  const int tx = lane & 7, ty = lane >> 3;
  const int m0 = blockIdx.x * 64;
  const int mat = blockIdx.y >> 3;
  const int n0 = (blockIdx.y & 7) * 64;
  const float* A    = mat == 0 ? p.A0 : (mat == 1 ? p.A1 : (mat == 2 ? p.A2 : p.A3));
  const float* W    = mat == 0 ? p.W0 : (mat == 1 ? p.W1 : (mat == 2 ? p.W2 : p.W3));
  const float* bias = mat == 0 ? p.b0 : (mat == 1 ? p.b1 : (mat == 2 ? p.b2 : p.b3));
  float* C          = mat == 0 ? p.C0 : (mat == 1 ? p.C1 : (mat == 2 ? p.C2 : p.C3));

  const int ar = lane >> 2;        // 0..15  (A row within quarter)
  const int ak = (lane & 3) * 4;   // 0,4,8,12 (A k offset)
  const int bk = lane >> 4;        // 0..3   (B k row within quarter)
  const int bc = (lane & 15) * 4;  // 0..60  (B col)

  float4 areg[4], breg[4];
#pragma unroll
  for (int q = 0; q < 4; q++) {
    areg[q] = *(const float4*)(A + (size_t)(m0 + ar + q * 16) * DD + ak);
    breg[q] = *(const float4*)(W + (size_t)(bk + q * 4) * DD + n0 + bc);
  }
#pragma unroll
  for (int q = 0; q < 4; q++) {
    As[0][ak + 0][ar + q * 16] = areg[q].x;
    As[0][ak + 1][ar + q * 16] = areg[q].y;
    As[0][ak + 2][ar + q * 16] = areg[q].z;
    As[0][ak + 3][ar + q * 16] = areg[q].w;
    *(float4*)&Bs[0][bk + q * 4][bc] = breg[q];
  }
  __syncthreads();

  float acc[8][8];
#pragma unroll
  for (int i = 0; i < 8; i++)
#pragma unroll
    for (int j = 0; j < 8; j++) acc[i][j] = 0.f;

  int cur = 0;
  for (int t = 0; t < DD / 16; t++) {
    // prefetch next tile into registers (stays in flight during FMAs)
    if (t + 1 < DD / 16) {
      const int k0 = (t + 1) * 16;
#pragma unroll
      for (int q = 0; q < 4; q++) {
        areg[q] = *(const float4*)(A + (size_t)(m0 + ar + q * 16) * DD + k0 + ak);
        breg[q] = *(const float4*)(W + (size_t)(k0 + bk + q * 4) * DD + n0 + bc);
      }
    }
#pragma unroll
    for (int kk = 0; kk < 16; kk++) {
      float4 a0 = *(const float4*)&As[cur][kk][ty * 8];
      float4 a1 = *(const float4*)&As[cur][kk][ty * 8 + 4];
      float4 b0 = *(const float4*)&Bs[cur][kk][tx * 8];
      float4 b1 = *(const float4*)&Bs[cur][kk][tx * 8 + 4];
      float a[8] = {a0.x, a0.y, a0.z, a0.w, a1.x, a1.y, a1.z, a1.w};
      float b[8] = {b0.x, b0.y, b0.z, b0.w, b1.x, b1.y, b1.z, b1.w};
#pragma unroll
      for (int i = 0; i < 8; i++)
#pragma unroll
        for (int j = 0; j < 8; j++) acc[i][j] = fmaf(a[i], b[j], acc[i][j]);
    }
    if (t + 1 < DD / 16) {
      const int nb = cur ^ 1;
#pragma unroll
      for (int q = 0; q < 4; q++) {
        As[nb][ak + 0][ar + q * 16] = areg[q].x;
        As[nb][ak + 1][ar + q * 16] = areg[q].y;
        As[nb][ak + 2][ar + q * 16] = areg[q].z;
        As[nb][ak + 3][ar + q * 16] = areg[q].w;
        *(float4*)&Bs[nb][bk + q * 4][bc] = breg[q];
      }
      __syncthreads();
      cur = nb;
    }
  }

  float bb[8];
#pragma unroll
  for (int j = 0; j < 8; j++) bb[j] = bias[n0 + tx * 8 + j];
#pragma unroll
  for (int i = 0; i < 8; i++) {
    const int m = m0 + ty * 8 + i;
    const float bs = p.bscale ? (float)p.bscale[m] : 1.0f;
    float4 o0, o1;
    o0.x = acc[i][0] + bs * bb[0];
    o0.y = acc[i][1] + bs * bb[1];
    o0.z = acc[i][2] + bs * bb[2];
    o0.w = acc[i][3] + bs * bb[3];
    o1.x = acc[i][4] + bs * bb[4];
    o1.y = acc[i][5] + bs * bb[5];
    o1.z = acc[i][6] + bs * bb[6];
    o1.w = acc[i][7] + bs * bb[7];
    *(float4*)(C + (size_t)m * DD + n0 + tx * 8) = o0;
    *(float4*)(C + (size_t)m * DD + n0 + tx * 8 + 4) = o1;
  }
}

// ---------------- batched SpMM pair: C[r] = sum_k vals[r,k] * B[cols[r,k]] ---
struct Spmm2 {
  const int* cA; const int* nA; const float* vA; const float* BA; float* CA;
  const int* cB; const int* nB; const float* vB; const float* BB; float* CB;
};

__global__ __launch_bounds__(256) void k_spmm2(Spmm2 p) {
  const int s = blockIdx.y;
  const int* cols = s == 0 ? p.cA : p.cB;
  const int* cnts = s == 0 ? p.nA : p.nB;
  const float* vals = s == 0 ? p.vA : p.vB;
  const float* B = s == 0 ? p.BA : p.BB;
  float* C = s == 0 ? p.CA : p.CB;
  const int r = blockIdx.x;
  const int t = threadIdx.x;
  __shared__ int scol[ELL];
  __shared__ float sval[ELL];
  const int cnt = cnts[r];
  if (t < ELL) {
    scol[t] = (t < cnt) ? cols[(size_t)r * ELL + t] : 0;
    sval[t] = (vals && t < cnt) ? vals[(size_t)r * ELL + t] : 1.0f;
  }
  __syncthreads();
  float a0 = 0.f, a1 = 0.f;
#pragma unroll 4
  for (int k = 0; k < cnt; k++) {
    const float* Bj = B + (size_t)scol[k] * DD;
    float v = sval[k];
    a0 = fmaf(v, Bj[t], a0);
    a1 = fmaf(v, Bj[t + 256], a1);
  }
  C[(size_t)r * DD + t] = a0;
  C[(size_t)r * DD + t + 256] = a1;
}

// ------------- SDDMM (masked QK^T) + row softmax (+ dense row write) ---------
__global__ __launch_bounds__(256) void k_sddmm(const int* __restrict__ cols,
                                               const int* __restrict__ cnts,
                                               const float* __restrict__ Q,
                                               const float* __restrict__ K,
                                               float* __restrict__ attval,
                                               float* __restrict__ dense) {
  const int r = blockIdx.x;
  const int t = threadIdx.x;
  const int lane = t & 63, wv = t >> 6;
  const int cnt = cnts[r];
  __shared__ int scol[ELL];
  __shared__ float ssc[ELL];
  if (t < ELL) scol[t] = (t < cnt) ? cols[(size_t)r * ELL + t] : 0;
  if (dense) {  // zero-fill this row (replaces global memset)
    float4 z = {0.f, 0.f, 0.f, 0.f};
    float4* dr = (float4*)(dense + (size_t)r * NN);
#pragma unroll
    for (int q = 0; q < 4; q++) dr[t + 256 * q] = z;
  }
  __syncthreads();
  const float* Qr = Q + (size_t)r * DD + lane * 8;
  float4 q0 = *reinterpret_cast<const float4*>(Qr);
  float4 q1 = *reinterpret_cast<const float4*>(Qr + 4);
  for (int k = wv; k < cnt; k += 4) {
    const float* Kj = K + (size_t)scol[k] * DD + lane * 8;
    float4 k0 = *reinterpret_cast<const float4*>(Kj);
    float4 k1 = *reinterpret_cast<const float4*>(Kj + 4);
    float s = q0.x * k0.x + q0.y * k0.y + q0.z * k0.z + q0.w * k0.w +
              q1.x * k1.x + q1.y * k1.y + q1.z * k1.z + q1.w * k1.w;
#pragma unroll
    for (int off = 32; off > 0; off >>= 1) s += __shfl_xor(s, off);
    if (lane == 0) ssc[k] = s;
  }
  __syncthreads();
  if (wv == 0) {
    float v0 = (lane < cnt) ? ssc[lane] : -INFINITY;
    float v1 = (lane + 64 < cnt) ? ssc[lane + 64] : -INFINITY;
    float mx = fmaxf(v0, v1);
#pragma unroll
    for (int off = 32; off > 0; off >>= 1) mx = fmaxf(mx, __shfl_xor(mx, off));
    float e0 = (lane < cnt) ? expf(v0 - mx) : 0.f;
    float e1 = (lane + 64 < cnt) ? expf(v1 - mx) : 0.f;
    float sm = e0 + e1;
#pragma unroll
    for (int off = 32; off > 0; off >>= 1) sm += __shfl_xor(sm, off);
    float inv = 1.f / sm;
    if (lane < cnt) ssc[lane] = e0 * inv;
    if (lane + 64 < cnt) ssc[lane + 64] = e1 * inv;
  }
  __syncthreads();
  if (t < cnt) {
    float v = ssc[t];
    attval[(size_t)r * ELL + t] = v;
    if (dense) dense[(size_t)r * NN + scol[t]] = v;
  }
}

// -------- fused: row-normalize 3 segments + mask + relu + classifier + lsm ---
__global__ __launch_bounds__(256) void k_norm_cls(const float* __restrict__ T0,
                                                  const float* __restrict__ T1,
                                                  const float* __restrict__ T2,
                                                  const float* __restrict__ hop,
                                                  const float* __restrict__ Wc,
                                                  const float* __restrict__ bc,
                                                  float* __restrict__ out) {
  const int r = blockIdx.x;
  const int t = threadIdx.x;
  const int lane = t & 63, wv = t >> 6;
  __shared__ __align__(16) float srow[1536];
  __shared__ float red[4];
  __shared__ float pr[6][40];
  float h0 = hop[0], h1 = hop[1], h2 = hop[2];
  float hm = fmaxf(h0, fmaxf(h1, h2));
  float e0 = expf(h0 - hm), e1 = expf(h1 - hm), e2 = expf(h2 - hm);
  float minv = 1.f / (e0 + e1 + e2);
  float mask[3] = {e0 * minv, e1 * minv, e2 * minv};
  const float* Ts[3] = {T0, T1, T2};
#pragma unroll
  for (int s = 0; s < 3; s++) {
    float x0 = Ts[s][(size_t)r * DD + t];
    float x1 = Ts[s][(size_t)r * DD + t + 256];
    float ss = x0 * x0 + x1 * x1;
#pragma unroll
    for (int off = 32; off > 0; off >>= 1) ss += __shfl_xor(ss, off);
    if (lane == 0) red[wv] = ss;
    __syncthreads();
    float tot = red[0] + red[1] + red[2] + red[3];
    float nrm = fmaxf(sqrtf(tot), 1e-12f);
    float sc = mask[s] / nrm;
    srow[s * DD + t] = fmaxf(x0 * sc, 0.f);
    srow[s * DD + t + 256] = fmaxf(x1 * sc, 0.f);
    __syncthreads();
  }
  float part = 0.f;
  const int col = t % 40, seg = t / 40;
  if (seg < 6) {
    const float* w = Wc + col;
#pragma unroll 4
    for (int k = seg * 256; k < seg * 256 + 256; k++)
      part = fmaf(srow[k], w[(size_t)k * 40], part);
    pr[seg][col] = part;
  }
  __syncthreads();
  if (t < 64) {
    float lg = -INFINITY;
    if (t < 40) {
      lg = bc[t];
#pragma unroll
      for (int s6 = 0; s6 < 6; s6++) lg += pr[s6][t];
    }
    float mx = lg;
#pragma unroll
    for (int off = 32; off > 0; off >>= 1) mx = fmaxf(mx, __shfl_xor(mx, off));
    float ex = (t < 40) ? expf(lg - mx) : 0.f;
    float sm = ex;
#pragma unroll
    for (int off = 32; off > 0; off >>= 1) sm += __shfl_xor(sm, off);
    float ls = logf(sm);
    if (t < 40) out[(size_t)r * 40 + t] = lg - mx - ls;
  }
}

extern "C" void kernel_launch(void* const* d_in, const int* in_sizes, int n_in,
                              void* d_out, int out_size, void* d_ws, size_t ws_size,
                              hipStream_t stream) {
  (void)in_sizes; (void)n_in; (void)out_size; (void)ws_size;
  const float* x    = (const float*)d_in[0];
  const float* adjA = (const float*)d_in[1];
  const float* adj1 = (const float*)d_in[2];
  const float* adj2 = (const float*)d_in[3];
  const float* hop  = (const float*)d_in[4];
  const float* Wfc0 = (const float*)d_in[5];  const float* bfc0 = (const float*)d_in[6];
  const float* Wfc1 = (const float*)d_in[7];  const float* bfc1 = (const float*)d_in[8];
  const float* Wfc2 = (const float*)d_in[9];  const float* bfc2 = (const float*)d_in[10];
  const float* Wq0  = (const float*)d_in[11]; const float* bq0  = (const float*)d_in[12];
  const float* Wk0  = (const float*)d_in[13]; const float* bk0  = (const float*)d_in[14];
  const float* Wq1  = (const float*)d_in[15]; const float* bq1  = (const float*)d_in[16];
  const float* Wk1  = (const float*)d_in[17]; const float* bk1  = (const float*)d_in[18];
  const float* Wc   = (const float*)d_in[19]; const float* bc   = (const float*)d_in[20];

  float* ws = (float*)d_ws;
  const size_t MD = (size_t)NN * DD;
  float* TMP0 = ws + 0 * MD;
  float* TMP1 = ws + 1 * MD;
  float* TMP2 = ws + 2 * MD;
  float* U1   = ws + 3 * MD;  // later reused as OUT1
  float* U2   = ws + 4 * MD;  // later reused as OUT2
  float* S5   = ws + 5 * MD;  // TATT1, then QB2
  float* S6   = ws + 6 * MD;  // TATT2, then KB2
  float* ATTV1 = ws + 7 * MD;
  float* ATTV2 = ATTV1 + (size_t)NN * ELL;
  int* ELLA = (int*)(ws + 8 * MD);
  int* ELL1 = ELLA + (size_t)NN * ELL;
  int* ELL2 = ELL1 + (size_t)NN * ELL;
  int* CNTA = ELL2 + (size_t)NN * ELL;
  int* CNT1 = CNTA + NN;
  int* CNT2 = CNT1 + NN;

  float* outLog = (float*)d_out;
  float* outAtt = outLog + (size_t)NN * 40;
  float* QB1 = outAtt;            // scratch in d_out, dead before zero-fill
  float* KB1 = outAtt + MD;

  Build3 pb{adjA, adj1, adj2, ELLA, ELL1, ELL2, CNTA, CNT1, CNT2};
  k_build3<<<dim3(NN / 4, 3), 256, 0, stream>>>(pb);

  // tmp_i = x @ W_fc_i + b_fc_i  (3 matrices, one dispatch)
  Gemm4 p1{x, x, x, nullptr, Wfc0, Wfc1, Wfc2, nullptr,
           bfc0, bfc1, bfc2, nullptr, TMP0, TMP1, TMP2, nullptr, nullptr};
  k_gemm64<<<dim3(64, 24), 64, 0, stream>>>(p1);

  // structural SpMM chains for both layers, batched pairwise
  Spmm2 s1{ELLA, CNTA, nullptr, TMP1, S5, ELLA, CNTA, nullptr, TMP2, S6};
  k_spmm2<<<dim3(NN, 2), 256, 0, stream>>>(s1);   // t_att for layers 1,2
  Spmm2 s2{ELLA, CNTA, nullptr, S5, U1, ELLA, CNTA, nullptr, S6, U2};
  k_spmm2<<<dim3(NN, 2), 256, 0, stream>>>(s2);   // U = A * t_att

  // Q/K for both layers: U@Wq + deg*bq etc. (4 matrices, one dispatch)
  Gemm4 p2{U1, U1, U2, U2, Wq0, Wk0, Wq1, Wk1,
           bq0, bk0, bq1, bk1, QB1, KB1, S5, S6, CNTA};
  k_gemm64<<<dim3(64, 32), 64, 0, stream>>>(p2);

  k_sddmm<<<NN, 256, 0, stream>>>(ELL1, CNT1, QB1, KB1, ATTV1, nullptr);
  k_sddmm<<<NN, 256, 0, stream>>>(ELL2, CNT2, S5, S6, ATTV2, outAtt);

  // att @ tmp for both layers
  Spmm2 s3{ELL1, CNT1, ATTV1, TMP1, U1, ELL2, CNT2, ATTV2, TMP2, U2};
  k_spmm2<<<dim3(NN, 2), 256, 0, stream>>>(s3);

  k_norm_cls<<<NN, 256, 0, stream>>>(TMP0, U1, U2, hop, Wc, bc, outLog);
}